// Round 7
// baseline (74.468 us; speedup 1.0000x reference)
//
#include <hip/hip_runtime.h>
#include <hip/hip_bf16.h>
#include <math.h>

#define SEQ   2048
#define H     1024
#define VOCAB 32000
#define GRID2 2048
#define NTHR  256

__device__ inline float4 ld4(const float* p) { return *reinterpret_cast<const float4*>(p); }
typedef float vfloat4 __attribute__((ext_vector_type(4)));
__device__ inline float4 ld4nt(const float* p) {
    vfloat4 v = __builtin_nontemporal_load(reinterpret_cast<const vfloat4*>(p));
    return make_float4(v.x, v.y, v.z, v.w);
}
__device__ inline float dot4(float4 a, float4 b) { return a.x*b.x + a.y*b.y + a.z*b.z + a.w*b.w; }
__device__ inline float sigmoidf(float x) { return 1.f / (1.f + expf(-x)); }

__device__ inline void omerge(float& m, float& s, float m2, float s2) {
    if (m2 > m) { s = s * __expf(m - m2) + s2; m = m2; }
    else if (s2 != 0.f) { s += s2 * __expf(m2 - m); }
}
__device__ inline float waveSum(float v) {
#pragma unroll
    for (int off = 32; off > 0; off >>= 1) v += __shfl_down(v, off, 64);
    return v;
}
__device__ inline void waveOmerge(float& m, float& s) {
#pragma unroll
    for (int off = 32; off > 0; off >>= 1) {
        float m2 = __shfl_down(m, off, 64), ss = __shfl_down(s, off, 64);
        omerge(m, s, m2, ss);
    }
}

// ---- device-scope block signal/wait ---------------------------------------
__device__ inline void blockSignal(unsigned* f) {
    __syncthreads();
    if (threadIdx.x == 0) {
        __threadfence();
        __hip_atomic_fetch_add(f, 1u, __ATOMIC_RELEASE, __HIP_MEMORY_SCOPE_AGENT);
    }
}
__device__ inline void blockWait(unsigned* f, unsigned target) {
    if (threadIdx.x == 0) {
        while (__hip_atomic_load(f, __ATOMIC_ACQUIRE, __HIP_MEMORY_SCOPE_AGENT) < target)
            __builtin_amdgcn_s_sleep(4);
        __threadfence();
    }
    __syncthreads();
}

// ws layout (floats):
//  [0..127]  flags (uint): f_h=+0, f_u=+16, f_e=+32, f_ctx=+48, f_l=+64
//  h     = ws+128  [1024]  } vcat contiguous [2048]
//  ctx   = ws+1152 [1024]  }
//  u     = ws+2176 [1024]
//  energ = ws+3200 [2048]
//  part_e = (float2*)(ws+5248) [256]
//  part_l = (float2*)(ws+5760) [2048]

__global__ __launch_bounds__(NTHR) void k_init(float* __restrict__ ws) {
    const int t = threadIdx.x;
    unsigned* fl = (unsigned*)ws;
    if (t < 128) fl[t] = 0u;
    float* ctx = ws + 1152;
    float* u   = ws + 2176;
    for (int k = t; k < H; k += NTHR) { u[k] = 0.f; ctx[k] = 0.f; }
}

__global__ __launch_bounds__(NTHR, 8) void k_main(
        const float* __restrict__ emb,  const float* __restrict__ lctx,
        const float* __restrict__ h0,   const float* __restrict__ W_ih,
        const float* __restrict__ W_hh, const float* __restrict__ b_ih,
        const float* __restrict__ b_hh, const int* __restrict__ widx,
        const float* __restrict__ enc,  const float* __restrict__ Wa,
        const float* __restrict__ Wl,   const float* __restrict__ bl,
        float* __restrict__ ws, float* __restrict__ out) {
    const int bid = blockIdx.x, t = threadIdx.x;
    const int wid = t >> 6, lane = t & 63;

    unsigned* f_h   = (unsigned*)ws + 0;
    unsigned* f_u   = (unsigned*)ws + 16;
    unsigned* f_e   = (unsigned*)ws + 32;
    unsigned* f_ctx = (unsigned*)ws + 48;
    unsigned* f_l   = (unsigned*)ws + 64;
    float*  vcat   = ws + 128;                // [2048] = h | ctx
    float*  h      = vcat;
    float*  ctx    = vcat + H;
    float*  u      = ws + 2176;
    float*  energ  = ws + 3200;
    float2* part_e = (float2*)(ws + 5248);
    float2* part_l = (float2*)(ws + 5760);

    __shared__ float  lg[12];
    __shared__ float  shh[16];
    __shared__ float  se[8];
    __shared__ float  shw[32];
    __shared__ float2 s2[4];

    // ======== P1: LSTM — blocks 0..1023, one block per output j ===========
    if (bid < 1024) {
        const int j = bid;
        const int w = widx[0];                 // int64 LE, value < 32000
        const float* xep = emb + (size_t)w * H;
        const float* wi = W_ih + (size_t)j * (2 * H);
        const float* wg = W_ih + (size_t)(j + 2 * H) * (2 * H);
        const float* wo = W_ih + (size_t)(j + 3 * H) * (2 * H);
        const float* vi = W_hh + (size_t)j * H;
        const float* vg = W_hh + (size_t)(j + 2 * H) * H;
        const float* vo = W_hh + (size_t)(j + 3 * H) * H;
        const int e = t * 4;
        float4 x0 = ld4(xep + e), x1 = ld4(lctx + e), x2 = ld4(h0 + e);
        // gates are single-use: non-temporal to keep Wl resident in L3
        float ai = dot4(ld4nt(wi + e), x0) + dot4(ld4nt(wi + H + e), x1) + dot4(ld4nt(vi + e), x2);
        float ag = dot4(ld4nt(wg + e), x0) + dot4(ld4nt(wg + H + e), x1) + dot4(ld4nt(vg + e), x2);
        float ao = dot4(ld4nt(wo + e), x0) + dot4(ld4nt(wo + H + e), x1) + dot4(ld4nt(vo + e), x2);
        ai = waveSum(ai); ag = waveSum(ag); ao = waveSum(ao);
        if (lane == 0) { lg[wid*3] = ai; lg[wid*3+1] = ag; lg[wid*3+2] = ao; }
        __syncthreads();
        if (t == 0) {
            float gi = 0.f, gg = 0.f, go = 0.f;
            for (int q = 0; q < 4; ++q) { gi += lg[q*3]; gg += lg[q*3+1]; go += lg[q*3+2]; }
            gi += b_ih[j] + b_hh[j];
            gg += b_ih[j + 2*H] + b_hh[j + 2*H];
            go += b_ih[j + 3*H] + b_hh[j + 3*H];
            float c = sigmoidf(gi) * tanhf(gg);  // c0 == 0 -> f-gate dead
            h[j] = sigmoidf(go) * tanhf(c);
        }
        blockSignal(f_h);
    }

    blockWait(f_h, 1024);   // ---- h complete ----

    if (bid >= 1024 && bid < 1280) {
        // ================= attention chain (256 blocks) ====================
        const int ab = bid - 1024;
        // --- u = Wa^T h : 64 rowgroups x 16 rows, 4 col slices ---
        {
            const int rg = ab >> 2, kb = ab & 3;
            if (t < 16) shh[t] = h[rg * 16 + t];
            __syncthreads();
            const int k = kb * 256 + t;
            float acc = 0.f;
#pragma unroll
            for (int jj = 0; jj < 16; ++jj)
                acc += Wa[(size_t)(rg * 16 + jj) * H + k] * shh[jj];
            atomicAdd(&u[k], acc);
            blockSignal(f_u);
            blockWait(f_u, 256);
        }
        // --- energies: 8 rows/block (2 per wave) + block (m,s) partial ---
        {
#pragma unroll
            for (int rr = 0; rr < 2; ++rr) {
                const int row = ab * 8 + wid * 2 + rr;
                const float* er = enc + (size_t)row * H;
                float acc = 0.f;
#pragma unroll
                for (int it = 0; it < 4; ++it) {
                    const int e = it * 256 + lane * 4;
                    acc += dot4(ld4(er + e), ld4(u + e));
                }
                acc = waveSum(acc);
                if (lane == 0) { energ[row] = acc; se[wid * 2 + rr] = acc; }
            }
            __syncthreads();
            if (t == 0) {
                float m = -INFINITY, s = 0.f;
                for (int q = 0; q < 8; ++q) omerge(m, s, se[q], 1.f);
                part_e[ab] = make_float2(m, s);
            }
            blockSignal(f_e);
            blockWait(f_e, 256);
        }
        // --- ctx = softmax(energ) @ enc : 64 rowgroups x 32 rows ---
        {
            float2 p = part_e[t];                 // 256 partials, one per thread
            float m = p.x, s = p.y;
            waveOmerge(m, s);
            if (lane == 0) s2[wid] = make_float2(m, s);
            __syncthreads();
            float M = s2[0].x, S = s2[0].y;
#pragma unroll
            for (int q = 1; q < 4; ++q) omerge(M, S, s2[q].x, s2[q].y);
            const float invS = 1.f / S;
            const int rg = ab >> 2, kb = ab & 3;
            __syncthreads();
            if (t < 32) shw[t] = __expf(energ[rg * 32 + t] - M) * invS;
            __syncthreads();
            const int k = kb * 256 + t;
            float acc = 0.f;
#pragma unroll
            for (int jj = 0; jj < 32; ++jj)
                acc += shw[jj] * enc[(size_t)(rg * 32 + jj) * H + k];
            atomicAdd(&ctx[k], acc);
            blockSignal(f_ctx);
            blockWait(f_ctx, 256);
        }
        // --- tail rows 28672..31999 end-to-end (vcat fully available) ---
        {
            const int aw = ab * 4 + wid;          // 0..1023
            float4 xv[8];
#pragma unroll
            for (int q = 0; q < 8; ++q) xv[q] = ld4(vcat + q * 256 + lane * 4);
            float lm = -INFINITY, ls = 0.f;
#pragma unroll
            for (int rr = 0; rr < 4; ++rr) {
                if (rr < 3 || aw < 256) {
                    const int r = 28672 + aw + 1024 * rr;
                    const float* wr = Wl + (size_t)r * (2 * H);
                    float a = 0.f;
#pragma unroll
                    for (int q = 0; q < 8; ++q)
                        a += dot4(ld4(wr + q * 256 + lane * 4), xv[q]);
                    a = waveSum(a);
                    if (lane == 0) {
                        float v = a + bl[r];
                        out[r] = v;
                        omerge(lm, ls, v, 1.f);
                    }
                }
            }
            if (lane == 0) s2[wid] = make_float2(lm, ls);
            __syncthreads();
            if (t == 0) {
                float M = s2[0].x, S = s2[0].y;
#pragma unroll
                for (int q = 1; q < 4; ++q) omerge(M, S, s2[q].x, s2[q].y);
                part_l[bid] = make_float2(M, S);
            }
            blockSignal(f_l);
        }
    } else {
        // ======== streamers: rows 0..28671, h-half then ctx-half ==========
        const int sw = (bid < 1024) ? bid * 4 + wid : (bid - 256) * 4 + wid; // 0..7167
        const int r0 = sw * 4;
        float4 xv[4];
#pragma unroll
        for (int q = 0; q < 4; ++q) xv[q] = ld4(h + q * 256 + lane * 4);
        float acc4[4];
#pragma unroll
        for (int rr = 0; rr < 4; ++rr) {
            const float* wr = Wl + (size_t)(r0 + rr) * (2 * H);
            float a = 0.f;
#pragma unroll
            for (int q = 0; q < 4; ++q)
                a += dot4(ld4(wr + q * 256 + lane * 4), xv[q]);
            acc4[rr] = a;
        }
        blockWait(f_ctx, 256);   // ---- ctx ready ----
#pragma unroll
        for (int q = 0; q < 4; ++q) xv[q] = ld4(ctx + q * 256 + lane * 4);
        float lm = -INFINITY, ls = 0.f;
#pragma unroll
        for (int rr = 0; rr < 4; ++rr) {
            const int r = r0 + rr;
            const float* wr = Wl + (size_t)r * (2 * H) + H;
            float a = acc4[rr];
#pragma unroll
            for (int q = 0; q < 4; ++q)
                a += dot4(ld4(wr + q * 256 + lane * 4), xv[q]);
            a = waveSum(a);
            if (lane == 0) {
                float v = a + bl[r];
                out[r] = v;
                omerge(lm, ls, v, 1.f);
            }
        }
        if (lane == 0) s2[wid] = make_float2(lm, ls);
        __syncthreads();
        if (t == 0) {
            float M = s2[0].x, S = s2[0].y;
#pragma unroll
            for (int q = 1; q < 4; ++q) omerge(M, S, s2[q].x, s2[q].y);
            part_l[bid] = make_float2(M, S);
        }
        blockSignal(f_l);
    }

    // ============ final: out = logits - lse (blocks 0..124) ================
    if (bid < 125) {
        blockWait(f_l, 2048);
        float m = -INFINITY, s = 0.f;
#pragma unroll
        for (int q = 0; q < 8; ++q) {
            float2 p = part_l[t + q * 256];
            omerge(m, s, p.x, p.y);
        }
        waveOmerge(m, s);
        if (lane == 0) s2[wid] = make_float2(m, s);
        __syncthreads();
        float M = s2[0].x, S = s2[0].y;
#pragma unroll
        for (int q = 1; q < 4; ++q) omerge(M, S, s2[q].x, s2[q].y);
        const float lse = M + logf(S);
        const int i = bid * 256 + t;              // 125*256 == 32000
        out[i] = out[i] - lse;
    }
}

// ======================= fallback path (round-5, proven 74.8 µs) ===========

__global__ __launch_bounds__(256) void k_lstm(
        const float* __restrict__ emb, const float* __restrict__ lctx,
        const float* __restrict__ h0,  const float* __restrict__ W_ih,
        const float* __restrict__ W_hh, const float* __restrict__ b_ih,
        const float* __restrict__ b_hh, const int* __restrict__ widx,
        float* __restrict__ h_out, float* __restrict__ u_zero,
        float* __restrict__ ctx_zero) {
    const int j = blockIdx.x, t = threadIdx.x;
    const int wid = t >> 6, lane = t & 63;
    if (j == 0) for (int k = t; k < H; k += 256) u_zero[k] = 0.f;
    if (j == 1) for (int k = t; k < H; k += 256) ctx_zero[k] = 0.f;
    const int w = widx[0];
    const float* embrow = emb + (size_t)w * H;
    const int ri = j, rg = j + 2 * H, ro = j + 3 * H;
    const float* wi_i = W_ih + (size_t)ri * (2 * H);
    const float* wi_g = W_ih + (size_t)rg * (2 * H);
    const float* wi_o = W_ih + (size_t)ro * (2 * H);
    const float* wh_i = W_hh + (size_t)ri * H;
    const float* wh_g = W_hh + (size_t)rg * H;
    const float* wh_o = W_hh + (size_t)ro * H;
    float ai = 0.f, ag = 0.f, ao = 0.f;
    { int e = t*4; float4 x = ld4(embrow+e);
      ai += dot4(ld4(wi_i+e),x); ag += dot4(ld4(wi_g+e),x); ao += dot4(ld4(wi_o+e),x); }
    { int e = t*4; float4 x = ld4(lctx+e);
      ai += dot4(ld4(wi_i+H+e),x); ag += dot4(ld4(wi_g+H+e),x); ao += dot4(ld4(wi_o+H+e),x); }
    { int e = t*4; float4 x = ld4(h0+e);
      ai += dot4(ld4(wh_i+e),x); ag += dot4(ld4(wh_g+e),x); ao += dot4(ld4(wh_o+e),x); }
    ai = waveSum(ai); ag = waveSum(ag); ao = waveSum(ao);
    __shared__ float lds[12];
    if (lane == 0) { lds[wid*3] = ai; lds[wid*3+1] = ag; lds[wid*3+2] = ao; }
    __syncthreads();
    if (t == 0) {
        float gi = 0.f, gg = 0.f, go = 0.f;
        for (int q = 0; q < 4; ++q) { gi += lds[q*3]; gg += lds[q*3+1]; go += lds[q*3+2]; }
        gi += b_ih[ri] + b_hh[ri];
        gg += b_ih[rg] + b_hh[rg];
        go += b_ih[ro] + b_hh[ro];
        float c = sigmoidf(gi) * tanhf(gg);
        h_out[j] = sigmoidf(go) * tanhf(c);
    }
}

__global__ __launch_bounds__(256) void k_wa(
        const float* __restrict__ Wa, const float* __restrict__ h,
        float* __restrict__ u) {
    const int k = blockIdx.x * 256 + threadIdx.x;
    const int j0 = blockIdx.y * 32;
    float acc = 0.f;
#pragma unroll 8
    for (int j = j0; j < j0 + 32; ++j) acc += Wa[(size_t)j * H + k] * h[j];
    atomicAdd(&u[k], acc);
}

__global__ __launch_bounds__(256) void k_energy(
        const float* __restrict__ enc, const float* __restrict__ u,
        float* __restrict__ energ, float2* __restrict__ part_e) {
    const int t = threadIdx.x, wid = t >> 6, lane = t & 63;
    const int row = blockIdx.x * 4 + wid;
    const float* er = enc + (size_t)row * H;
    float acc = 0.f;
#pragma unroll
    for (int it = 0; it < 4; ++it) { int e = it*256 + lane*4; acc += dot4(ld4(er+e), ld4(u+e)); }
    acc = waveSum(acc);
    __shared__ float se[4];
    if (lane == 0) { energ[row] = acc; se[wid] = acc; }
    __syncthreads();
    if (t == 0) {
        float m = fmaxf(fmaxf(se[0], se[1]), fmaxf(se[2], se[3]));
        float s = __expf(se[0]-m) + __expf(se[1]-m) + __expf(se[2]-m) + __expf(se[3]-m);
        part_e[blockIdx.x] = make_float2(m, s);
    }
}

__global__ __launch_bounds__(256) void k_ctx(
        const float* __restrict__ enc, const float* __restrict__ energ,
        const float2* __restrict__ part_e, float* __restrict__ ctx) {
    const int t = threadIdx.x, wid = t >> 6, lane = t & 63;
    __shared__ float2 s2[4];
    __shared__ float sh[64];
    float2 a = part_e[t], b = part_e[t + 256];
    float m = a.x, s = a.y;
    omerge(m, s, b.x, b.y);
    waveOmerge(m, s);
    if (lane == 0) s2[wid] = make_float2(m, s);
    __syncthreads();
    float M = s2[0].x, S = s2[0].y;
#pragma unroll
    for (int q = 1; q < 4; ++q) omerge(M, S, s2[q].x, s2[q].y);
    const float invS = 1.f / S;
    const int j0 = (blockIdx.x >> 2) * 64;
    __syncthreads();
    if (t < 64) sh[t] = __expf(energ[j0 + t] - M) * invS;
    __syncthreads();
    const int k = (blockIdx.x & 3) * 256 + t;
    float acc = 0.f;
#pragma unroll 8
    for (int jj = 0; jj < 64; ++jj) acc += sh[jj] * enc[(size_t)(j0 + jj) * H + k];
    atomicAdd(&ctx[k], acc);
}

__global__ __launch_bounds__(256) void k_logits(
        const float* __restrict__ Wl, const float* __restrict__ vcat,
        const float* __restrict__ bl, float* __restrict__ logits,
        float2* __restrict__ part_l) {
    const int t = threadIdx.x, wid = t >> 6, lane = t & 63;
    const int gw = blockIdx.x * 4 + wid;
    float4 xv[8];
#pragma unroll
    for (int q = 0; q < 8; ++q) xv[q] = ld4(vcat + q * 256 + lane * 4);
    float lm = -INFINITY, ls = 0.f;
#pragma unroll
    for (int rr = 0; rr < 4; ++rr) {
        const int row = gw * 4 + rr;
        const float* wr = Wl + (size_t)row * (2 * H);
        float acc = 0.f;
#pragma unroll
        for (int q = 0; q < 8; ++q)
            acc += dot4(ld4(wr + q * 256 + lane * 4), xv[q]);
        acc = waveSum(acc);
        if (lane == 0) {
            float v = acc + bl[row];
            logits[row] = v;
            omerge(lm, ls, v, 1.f);
        }
    }
    __shared__ float2 s2[4];
    if (lane == 0) s2[wid] = make_float2(lm, ls);
    __syncthreads();
    if (t == 0) {
        float M = s2[0].x, S = s2[0].y;
#pragma unroll
        for (int q = 1; q < 4; ++q) omerge(M, S, s2[q].x, s2[q].y);
        part_l[blockIdx.x] = make_float2(M, S);
    }
}

__global__ __launch_bounds__(256) void k_final(
        const float* __restrict__ logits, const float2* __restrict__ part_l,
        float* __restrict__ out) {
    const int t = threadIdx.x, wid = t >> 6, lane = t & 63;
    __shared__ float2 s2[4];
    float m = -INFINITY, s = 0.f;
    for (int i = t; i < 2000; i += 256) {
        float2 p = part_l[i];
        omerge(m, s, p.x, p.y);
    }
    waveOmerge(m, s);
    if (lane == 0) s2[wid] = make_float2(m, s);
    __syncthreads();
    float M = s2[0].x, S = s2[0].y;
#pragma unroll
    for (int q = 1; q < 4; ++q) omerge(M, S, s2[q].x, s2[q].y);
    const float lse = M + logf(S);
    const int i = blockIdx.x * 256 + t;
    out[i] = logits[i] - lse;
}

extern "C" void kernel_launch(void* const* d_in, const int* in_sizes, int n_in,
                              void* d_out, int out_size, void* d_ws, size_t ws_size,
                              hipStream_t stream) {
    const int*   widx = (const int*)d_in[0];
    const float* lctx = (const float*)d_in[1];
    const float* h0   = (const float*)d_in[2];
    const float* enc  = (const float*)d_in[3];
    const float* emb  = (const float*)d_in[4];
    const float* W_ih = (const float*)d_in[5];
    const float* W_hh = (const float*)d_in[6];
    const float* b_ih = (const float*)d_in[7];
    const float* b_hh = (const float*)d_in[8];
    const float* Wa   = (const float*)d_in[9];
    // d_in[10] (ba): dropped — constant shift under softmax
    const float* Wl   = (const float*)d_in[11];
    const float* bl   = (const float*)d_in[12];
    float* out = (float*)d_out;
    float* ws  = (float*)d_ws;

    // deadlock guard: persistent path requires all GRID2 blocks co-resident
    int occ = 0, nCU = 0, dev = 0;
    hipGetDevice(&dev);
    hipDeviceGetAttribute(&nCU, hipDeviceAttributeMultiprocessorCount, dev);
    hipError_t oe = hipOccupancyMaxActiveBlocksPerMultiprocessor(
        &occ, (const void*)k_main, NTHR, 0);
    const bool persistent_ok = (oe == hipSuccess) && ((long)occ * nCU >= GRID2);

    if (persistent_ok) {
        k_init<<<1, NTHR, 0, stream>>>(ws);
        k_main<<<GRID2, NTHR, 0, stream>>>(emb, lctx, h0, W_ih, W_hh, b_ih,
                                           b_hh, widx, enc, Wa, Wl, bl, ws, out);
    } else {
        float*  h      = ws;
        float*  ctx    = ws + 1024;
        float*  u      = ws + 2048;
        float*  energ  = ws + 3072;
        float2* part_e = (float2*)(ws + 5120);
        float2* part_l = (float2*)(ws + 6144);
        float*  logits = ws + 10240;
        k_lstm  <<<1024, 256, 0, stream>>>(emb, lctx, h0, W_ih, W_hh, b_ih, b_hh, widx, h, u, ctx);
        k_wa    <<<dim3(4, 32), 256, 0, stream>>>(Wa, h, u);
        k_energy<<<512, 256, 0, stream>>>(enc, u, energ, part_e);
        k_ctx   <<<128, 256, 0, stream>>>(enc, energ, part_e, ctx);
        k_logits<<<2000, 256, 0, stream>>>(Wl, ws /*vcat*/, bl, logits, part_l);
        k_final <<<125, 256, 0, stream>>>(logits, part_l, out);
    }
}

// Round 8
// 73.293 us; speedup vs baseline: 1.0160x; 1.0160x over previous
//
#include <hip/hip_runtime.h>
#include <hip/hip_bf16.h>
#include <math.h>

#define SEQ   2048
#define H     1024
#define VOCAB 32000
#define GRID2 2048
#define NTHR  256

__device__ inline float4 ld4(const float* p) { return *reinterpret_cast<const float4*>(p); }
__device__ inline float dot4(float4 a, float4 b) { return a.x*b.x + a.y*b.y + a.z*b.z + a.w*b.w; }
__device__ inline float sigmoidf(float x) { return 1.f / (1.f + expf(-x)); }

__device__ inline void omerge(float& m, float& s, float m2, float s2) {
    if (m2 > m) { s = s * __expf(m - m2) + s2; m = m2; }
    else if (s2 != 0.f) { s += s2 * __expf(m2 - m); }
}
__device__ inline float waveSum(float v) {
#pragma unroll
    for (int off = 32; off > 0; off >>= 1) v += __shfl_down(v, off, 64);
    return v;
}
__device__ inline void waveOmerge(float& m, float& s) {
#pragma unroll
    for (int off = 32; off > 0; off >>= 1) {
        float m2 = __shfl_down(m, off, 64), ss = __shfl_down(s, off, 64);
        omerge(m, s, m2, ss);
    }
}

// ---- sharded device-scope signal/wait -------------------------------------
// Each flag group = 16 shards x 32 uints (128 B apart). Adders pick shard by
// blockIdx; waiters sum all 16 shards. Exponential-backoff polling.
#define SHARDS 16
#define SHSTRIDE 32

__device__ inline void blockSignalSh(unsigned* f) {
    __syncthreads();
    if (threadIdx.x == 0) {
        __threadfence();
        __hip_atomic_fetch_add(&f[(blockIdx.x & (SHARDS - 1)) * SHSTRIDE], 1u,
                               __ATOMIC_RELEASE, __HIP_MEMORY_SCOPE_AGENT);
    }
}
__device__ inline unsigned shSum(unsigned* f) {
    unsigned sum = 0;
#pragma unroll
    for (int q = 0; q < SHARDS; ++q)
        sum += __hip_atomic_load(&f[q * SHSTRIDE], __ATOMIC_RELAXED,
                                 __HIP_MEMORY_SCOPE_AGENT);
    return sum;
}
// slow wait: backoff up to sleep(64) (~2.7us period) for big fan-in syncs
__device__ inline void blockWaitSlow(unsigned* f, unsigned target) {
    if (threadIdx.x == 0) {
        int it = 0;
        while (shSum(f) < target) {
            if (it < 2)       __builtin_amdgcn_s_sleep(1);
            else if (it < 4)  __builtin_amdgcn_s_sleep(2);
            else if (it < 6)  __builtin_amdgcn_s_sleep(4);
            else if (it < 8)  __builtin_amdgcn_s_sleep(8);
            else if (it < 10) __builtin_amdgcn_s_sleep(16);
            else if (it < 12) __builtin_amdgcn_s_sleep(32);
            else              __builtin_amdgcn_s_sleep(64);
            ++it;
        }
        __threadfence();
    }
    __syncthreads();
}
// fast wait: cap at sleep(8) for small 256-block syncs (latency-critical)
__device__ inline void blockWaitFast(unsigned* f, unsigned target) {
    if (threadIdx.x == 0) {
        int it = 0;
        while (shSum(f) < target) {
            if (it < 2)      __builtin_amdgcn_s_sleep(1);
            else if (it < 4) __builtin_amdgcn_s_sleep(2);
            else if (it < 6) __builtin_amdgcn_s_sleep(4);
            else             __builtin_amdgcn_s_sleep(8);
            ++it;
        }
        __threadfence();
    }
    __syncthreads();
}

// ws layout (floats):
//  flags: [0..2560) as uints — 5 groups x 512: f_h=+0, f_u=+512, f_e=+1024,
//         f_ctx=+1536, f_l=+2048
//  h     = ws+2560 [1024]  } vcat contiguous [2048]
//  ctx   = ws+3584 [1024]  }
//  u     = ws+4608 [1024]
//  energ = ws+5632 [2048]
//  part_e = (float2*)(ws+7680) [256]
//  part_l = (float2*)(ws+8192) [2048]

__global__ __launch_bounds__(NTHR) void k_init(float* __restrict__ ws) {
    const int t = threadIdx.x;
    unsigned* fl = (unsigned*)ws;
    for (int k = t; k < 2560; k += NTHR) fl[k] = 0u;
    float* ctx = ws + 3584;
    float* u   = ws + 4608;
    for (int k = t; k < H; k += NTHR) { u[k] = 0.f; ctx[k] = 0.f; }
}

__global__ __launch_bounds__(NTHR, 8) void k_main(
        const float* __restrict__ emb,  const float* __restrict__ lctx,
        const float* __restrict__ h0,   const float* __restrict__ W_ih,
        const float* __restrict__ W_hh, const float* __restrict__ b_ih,
        const float* __restrict__ b_hh, const int* __restrict__ widx,
        const float* __restrict__ enc,  const float* __restrict__ Wa,
        const float* __restrict__ Wl,   const float* __restrict__ bl,
        float* __restrict__ ws, float* __restrict__ out) {
    const int bid = blockIdx.x, t = threadIdx.x;
    const int wid = t >> 6, lane = t & 63;

    unsigned* f_h   = (unsigned*)ws + 0;
    unsigned* f_u   = (unsigned*)ws + 512;
    unsigned* f_e   = (unsigned*)ws + 1024;
    unsigned* f_ctx = (unsigned*)ws + 1536;
    unsigned* f_l   = (unsigned*)ws + 2048;
    float*  vcat   = ws + 2560;               // [2048] = h | ctx
    float*  h      = vcat;
    float*  ctx    = vcat + H;
    float*  u      = ws + 4608;
    float*  energ  = ws + 5632;
    float2* part_e = (float2*)(ws + 7680);
    float2* part_l = (float2*)(ws + 8192);

    __shared__ float  lg[12];
    __shared__ float  shh[16];
    __shared__ float  se[8];
    __shared__ float  shw[32];
    __shared__ float2 s2[4];

    // ======== P1: LSTM — blocks 0..1023, one block per output j ===========
    if (bid < 1024) {
        const int j = bid;
        const int w = widx[0];                 // int64 LE, value < 32000
        const float* xep = emb + (size_t)w * H;
        const float* wi = W_ih + (size_t)j * (2 * H);
        const float* wg = W_ih + (size_t)(j + 2 * H) * (2 * H);
        const float* wo = W_ih + (size_t)(j + 3 * H) * (2 * H);
        const float* vi = W_hh + (size_t)j * H;
        const float* vg = W_hh + (size_t)(j + 2 * H) * H;
        const float* vo = W_hh + (size_t)(j + 3 * H) * H;
        const int e = t * 4;
        float4 x0 = ld4(xep + e), x1 = ld4(lctx + e), x2 = ld4(h0 + e);
        float ai = dot4(ld4(wi + e), x0) + dot4(ld4(wi + H + e), x1) + dot4(ld4(vi + e), x2);
        float ag = dot4(ld4(wg + e), x0) + dot4(ld4(wg + H + e), x1) + dot4(ld4(vg + e), x2);
        float ao = dot4(ld4(wo + e), x0) + dot4(ld4(wo + H + e), x1) + dot4(ld4(vo + e), x2);
        ai = waveSum(ai); ag = waveSum(ag); ao = waveSum(ao);
        if (lane == 0) { lg[wid*3] = ai; lg[wid*3+1] = ag; lg[wid*3+2] = ao; }
        __syncthreads();
        if (t == 0) {
            float gi = 0.f, gg = 0.f, go = 0.f;
            for (int q = 0; q < 4; ++q) { gi += lg[q*3]; gg += lg[q*3+1]; go += lg[q*3+2]; }
            gi += b_ih[j] + b_hh[j];
            gg += b_ih[j + 2*H] + b_hh[j + 2*H];
            go += b_ih[j + 3*H] + b_hh[j + 3*H];
            float c = sigmoidf(gi) * tanhf(gg);  // c0 == 0 -> f-gate dead
            h[j] = sigmoidf(go) * tanhf(c);
        }
        blockSignalSh(f_h);
    }

    blockWaitSlow(f_h, 1024);   // ---- h complete ----

    if (bid >= 1024 && bid < 1280) {
        // ================= attention chain (256 blocks) ====================
        const int ab = bid - 1024;
        // --- u = Wa^T h : 64 rowgroups x 16 rows, 4 col slices ---
        {
            const int rg = ab >> 2, kb = ab & 3;
            if (t < 16) shh[t] = h[rg * 16 + t];
            __syncthreads();
            const int k = kb * 256 + t;
            float acc = 0.f;
#pragma unroll
            for (int jj = 0; jj < 16; ++jj)
                acc += Wa[(size_t)(rg * 16 + jj) * H + k] * shh[jj];
            atomicAdd(&u[k], acc);
            blockSignalSh(f_u);
            blockWaitFast(f_u, 256);
        }
        // --- energies: 8 rows/block (2 per wave) + block (m,s) partial ---
        {
#pragma unroll
            for (int rr = 0; rr < 2; ++rr) {
                const int row = ab * 8 + wid * 2 + rr;
                const float* er = enc + (size_t)row * H;
                float acc = 0.f;
#pragma unroll
                for (int it = 0; it < 4; ++it) {
                    const int e = it * 256 + lane * 4;
                    acc += dot4(ld4(er + e), ld4(u + e));
                }
                acc = waveSum(acc);
                if (lane == 0) { energ[row] = acc; se[wid * 2 + rr] = acc; }
            }
            __syncthreads();
            if (t == 0) {
                float m = -INFINITY, s = 0.f;
                for (int q = 0; q < 8; ++q) omerge(m, s, se[q], 1.f);
                part_e[ab] = make_float2(m, s);
            }
            blockSignalSh(f_e);
            blockWaitFast(f_e, 256);
        }
        // --- ctx = softmax(energ) @ enc : 64 rowgroups x 32 rows ---
        {
            float2 p = part_e[t];                 // 256 partials, one per thread
            float m = p.x, s = p.y;
            waveOmerge(m, s);
            if (lane == 0) s2[wid] = make_float2(m, s);
            __syncthreads();
            float M = s2[0].x, S = s2[0].y;
#pragma unroll
            for (int q = 1; q < 4; ++q) omerge(M, S, s2[q].x, s2[q].y);
            const float invS = 1.f / S;
            const int rg = ab >> 2, kb = ab & 3;
            __syncthreads();
            if (t < 32) shw[t] = __expf(energ[rg * 32 + t] - M) * invS;
            __syncthreads();
            const int k = kb * 256 + t;
            float acc = 0.f;
#pragma unroll
            for (int jj = 0; jj < 32; ++jj)
                acc += shw[jj] * enc[(size_t)(rg * 32 + jj) * H + k];
            atomicAdd(&ctx[k], acc);
            blockSignalSh(f_ctx);
            blockWaitFast(f_ctx, 256);
        }
        // --- tail rows 28672..31999 end-to-end (vcat fully available) ---
        {
            const int aw = ab * 4 + wid;          // 0..1023
            float4 xv[8];
#pragma unroll
            for (int q = 0; q < 8; ++q) xv[q] = ld4(vcat + q * 256 + lane * 4);
            float lm = -INFINITY, ls = 0.f;
#pragma unroll
            for (int rr = 0; rr < 4; ++rr) {
                if (rr < 3 || aw < 256) {
                    const int r = 28672 + aw + 1024 * rr;
                    const float* wr = Wl + (size_t)r * (2 * H);
                    float a = 0.f;
#pragma unroll
                    for (int q = 0; q < 8; ++q)
                        a += dot4(ld4(wr + q * 256 + lane * 4), xv[q]);
                    a = waveSum(a);
                    if (lane == 0) {
                        float v = a + bl[r];
                        out[r] = v;
                        omerge(lm, ls, v, 1.f);
                    }
                }
            }
            if (lane == 0) s2[wid] = make_float2(lm, ls);
            __syncthreads();
            if (t == 0) {
                float M = s2[0].x, S = s2[0].y;
#pragma unroll
                for (int q = 1; q < 4; ++q) omerge(M, S, s2[q].x, s2[q].y);
                part_l[bid] = make_float2(M, S);
            }
            blockSignalSh(f_l);
        }
    } else {
        // ======== streamers: rows 0..28671, h-half then ctx-half ==========
        const int sw = (bid < 1024) ? bid * 4 + wid : (bid - 256) * 4 + wid; // 0..7167
        const int r0 = sw * 4;
        float4 xv[4];
#pragma unroll
        for (int q = 0; q < 4; ++q) xv[q] = ld4(h + q * 256 + lane * 4);
        float acc4[4];
#pragma unroll
        for (int rr = 0; rr < 4; ++rr) {
            const float* wr = Wl + (size_t)(r0 + rr) * (2 * H);
            float a = 0.f;
#pragma unroll
            for (int q = 0; q < 4; ++q)
                a += dot4(ld4(wr + q * 256 + lane * 4), xv[q]);
            acc4[rr] = a;
        }
        blockWaitSlow(f_ctx, 256);   // ---- ctx ready (usually already) ----
#pragma unroll
        for (int q = 0; q < 4; ++q) xv[q] = ld4(ctx + q * 256 + lane * 4);
        float lm = -INFINITY, ls = 0.f;
#pragma unroll
        for (int rr = 0; rr < 4; ++rr) {
            const int r = r0 + rr;
            const float* wr = Wl + (size_t)r * (2 * H) + H;
            float a = acc4[rr];
#pragma unroll
            for (int q = 0; q < 4; ++q)
                a += dot4(ld4(wr + q * 256 + lane * 4), xv[q]);
            a = waveSum(a);
            if (lane == 0) {
                float v = a + bl[r];
                out[r] = v;
                omerge(lm, ls, v, 1.f);
            }
        }
        if (lane == 0) s2[wid] = make_float2(lm, ls);
        __syncthreads();
        if (t == 0) {
            float M = s2[0].x, S = s2[0].y;
#pragma unroll
            for (int q = 1; q < 4; ++q) omerge(M, S, s2[q].x, s2[q].y);
            part_l[bid] = make_float2(M, S);
        }
        blockSignalSh(f_l);
    }

    // ============ final: out = logits - lse (blocks 0..124) ================
    if (bid < 125) {
        blockWaitSlow(f_l, 2048);
        float m = -INFINITY, s = 0.f;
#pragma unroll
        for (int q = 0; q < 8; ++q) {
            float2 p = part_l[t + q * 256];
            omerge(m, s, p.x, p.y);
        }
        waveOmerge(m, s);
        if (lane == 0) s2[wid] = make_float2(m, s);
        __syncthreads();
        float M = s2[0].x, S = s2[0].y;
#pragma unroll
        for (int q = 1; q < 4; ++q) omerge(M, S, s2[q].x, s2[q].y);
        const float lse = M + logf(S);
        const int i = bid * 256 + t;              // 125*256 == 32000
        out[i] = out[i] - lse;
    }
}

// ======================= fallback path (round-5, proven 74.8 µs) ===========

__global__ __launch_bounds__(256) void k_lstm(
        const float* __restrict__ emb, const float* __restrict__ lctx,
        const float* __restrict__ h0,  const float* __restrict__ W_ih,
        const float* __restrict__ W_hh, const float* __restrict__ b_ih,
        const float* __restrict__ b_hh, const int* __restrict__ widx,
        float* __restrict__ h_out, float* __restrict__ u_zero,
        float* __restrict__ ctx_zero) {
    const int j = blockIdx.x, t = threadIdx.x;
    const int wid = t >> 6, lane = t & 63;
    if (j == 0) for (int k = t; k < H; k += 256) u_zero[k] = 0.f;
    if (j == 1) for (int k = t; k < H; k += 256) ctx_zero[k] = 0.f;
    const int w = widx[0];
    const float* embrow = emb + (size_t)w * H;
    const int ri = j, rg = j + 2 * H, ro = j + 3 * H;
    const float* wi_i = W_ih + (size_t)ri * (2 * H);
    const float* wi_g = W_ih + (size_t)rg * (2 * H);
    const float* wi_o = W_ih + (size_t)ro * (2 * H);
    const float* wh_i = W_hh + (size_t)ri * H;
    const float* wh_g = W_hh + (size_t)rg * H;
    const float* wh_o = W_hh + (size_t)ro * H;
    float ai = 0.f, ag = 0.f, ao = 0.f;
    { int e = t*4; float4 x = ld4(embrow+e);
      ai += dot4(ld4(wi_i+e),x); ag += dot4(ld4(wi_g+e),x); ao += dot4(ld4(wi_o+e),x); }
    { int e = t*4; float4 x = ld4(lctx+e);
      ai += dot4(ld4(wi_i+H+e),x); ag += dot4(ld4(wi_g+H+e),x); ao += dot4(ld4(wi_o+H+e),x); }
    { int e = t*4; float4 x = ld4(h0+e);
      ai += dot4(ld4(wh_i+e),x); ag += dot4(ld4(wh_g+e),x); ao += dot4(ld4(wh_o+e),x); }
    ai = waveSum(ai); ag = waveSum(ag); ao = waveSum(ao);
    __shared__ float lds[12];
    if (lane == 0) { lds[wid*3] = ai; lds[wid*3+1] = ag; lds[wid*3+2] = ao; }
    __syncthreads();
    if (t == 0) {
        float gi = 0.f, gg = 0.f, go = 0.f;
        for (int q = 0; q < 4; ++q) { gi += lds[q*3]; gg += lds[q*3+1]; go += lds[q*3+2]; }
        gi += b_ih[ri] + b_hh[ri];
        gg += b_ih[rg] + b_hh[rg];
        go += b_ih[ro] + b_hh[ro];
        float c = sigmoidf(gi) * tanhf(gg);
        h_out[j] = sigmoidf(go) * tanhf(c);
    }
}

__global__ __launch_bounds__(256) void k_wa(
        const float* __restrict__ Wa, const float* __restrict__ h,
        float* __restrict__ u) {
    const int k = blockIdx.x * 256 + threadIdx.x;
    const int j0 = blockIdx.y * 32;
    float acc = 0.f;
#pragma unroll 8
    for (int j = j0; j < j0 + 32; ++j) acc += Wa[(size_t)j * H + k] * h[j];
    atomicAdd(&u[k], acc);
}

__global__ __launch_bounds__(256) void k_energy(
        const float* __restrict__ enc, const float* __restrict__ u,
        float* __restrict__ energ, float2* __restrict__ part_e) {
    const int t = threadIdx.x, wid = t >> 6, lane = t & 63;
    const int row = blockIdx.x * 4 + wid;
    const float* er = enc + (size_t)row * H;
    float acc = 0.f;
#pragma unroll
    for (int it = 0; it < 4; ++it) { int e = it*256 + lane*4; acc += dot4(ld4(er+e), ld4(u+e)); }
    acc = waveSum(acc);
    __shared__ float se[4];
    if (lane == 0) { energ[row] = acc; se[wid] = acc; }
    __syncthreads();
    if (t == 0) {
        float m = fmaxf(fmaxf(se[0], se[1]), fmaxf(se[2], se[3]));
        float s = __expf(se[0]-m) + __expf(se[1]-m) + __expf(se[2]-m) + __expf(se[3]-m);
        part_e[blockIdx.x] = make_float2(m, s);
    }
}

__global__ __launch_bounds__(256) void k_ctx(
        const float* __restrict__ enc, const float* __restrict__ energ,
        const float2* __restrict__ part_e, float* __restrict__ ctx) {
    const int t = threadIdx.x, wid = t >> 6, lane = t & 63;
    __shared__ float2 s2[4];
    __shared__ float sh[64];
    float2 a = part_e[t], b = part_e[t + 256];
    float m = a.x, s = a.y;
    omerge(m, s, b.x, b.y);
    waveOmerge(m, s);
    if (lane == 0) s2[wid] = make_float2(m, s);
    __syncthreads();
    float M = s2[0].x, S = s2[0].y;
#pragma unroll
    for (int q = 1; q < 4; ++q) omerge(M, S, s2[q].x, s2[q].y);
    const float invS = 1.f / S;
    const int j0 = (blockIdx.x >> 2) * 64;
    __syncthreads();
    if (t < 64) sh[t] = __expf(energ[j0 + t] - M) * invS;
    __syncthreads();
    const int k = (blockIdx.x & 3) * 256 + t;
    float acc = 0.f;
#pragma unroll 8
    for (int jj = 0; jj < 64; ++jj) acc += sh[jj] * enc[(size_t)(j0 + jj) * H + k];
    atomicAdd(&ctx[k], acc);
}

__global__ __launch_bounds__(256) void k_logits(
        const float* __restrict__ Wl, const float* __restrict__ vcat,
        const float* __restrict__ bl, float* __restrict__ logits,
        float2* __restrict__ part_l) {
    const int t = threadIdx.x, wid = t >> 6, lane = t & 63;
    const int gw = blockIdx.x * 4 + wid;
    float4 xv[8];
#pragma unroll
    for (int q = 0; q < 8; ++q) xv[q] = ld4(vcat + q * 256 + lane * 4);
    float lm = -INFINITY, ls = 0.f;
#pragma unroll
    for (int rr = 0; rr < 4; ++rr) {
        const int row = gw * 4 + rr;
        const float* wr = Wl + (size_t)row * (2 * H);
        float acc = 0.f;
#pragma unroll
        for (int q = 0; q < 8; ++q)
            acc += dot4(ld4(wr + q * 256 + lane * 4), xv[q]);
        acc = waveSum(acc);
        if (lane == 0) {
            float v = acc + bl[row];
            logits[row] = v;
            omerge(lm, ls, v, 1.f);
        }
    }
    __shared__ float2 s2[4];
    if (lane == 0) s2[wid] = make_float2(lm, ls);
    __syncthreads();
    if (t == 0) {
        float M = s2[0].x, S = s2[0].y;
#pragma unroll
        for (int q = 1; q < 4; ++q) omerge(M, S, s2[q].x, s2[q].y);
        part_l[blockIdx.x] = make_float2(M, S);
    }
}

__global__ __launch_bounds__(256) void k_final(
        const float* __restrict__ logits, const float2* __restrict__ part_l,
        float* __restrict__ out) {
    const int t = threadIdx.x, wid = t >> 6, lane = t & 63;
    __shared__ float2 s2[4];
    float m = -INFINITY, s = 0.f;
    for (int i = t; i < 2000; i += 256) {
        float2 p = part_l[i];
        omerge(m, s, p.x, p.y);
    }
    waveOmerge(m, s);
    if (lane == 0) s2[wid] = make_float2(m, s);
    __syncthreads();
    float M = s2[0].x, S = s2[0].y;
#pragma unroll
    for (int q = 1; q < 4; ++q) omerge(M, S, s2[q].x, s2[q].y);
    const float lse = M + logf(S);
    const int i = blockIdx.x * 256 + t;
    out[i] = logits[i] - lse;
}

extern "C" void kernel_launch(void* const* d_in, const int* in_sizes, int n_in,
                              void* d_out, int out_size, void* d_ws, size_t ws_size,
                              hipStream_t stream) {
    const int*   widx = (const int*)d_in[0];
    const float* lctx = (const float*)d_in[1];
    const float* h0   = (const float*)d_in[2];
    const float* enc  = (const float*)d_in[3];
    const float* emb  = (const float*)d_in[4];
    const float* W_ih = (const float*)d_in[5];
    const float* W_hh = (const float*)d_in[6];
    const float* b_ih = (const float*)d_in[7];
    const float* b_hh = (const float*)d_in[8];
    const float* Wa   = (const float*)d_in[9];
    // d_in[10] (ba): dropped — constant shift under softmax
    const float* Wl   = (const float*)d_in[11];
    const float* bl   = (const float*)d_in[12];
    float* out = (float*)d_out;
    float* ws  = (float*)d_ws;

    // deadlock guard: persistent path requires all GRID2 blocks co-resident
    int occ = 0, nCU = 0, dev = 0;
    hipGetDevice(&dev);
    hipDeviceGetAttribute(&nCU, hipDeviceAttributeMultiprocessorCount, dev);
    hipError_t oe = hipOccupancyMaxActiveBlocksPerMultiprocessor(
        &occ, (const void*)k_main, NTHR, 0);
    const bool persistent_ok = (oe == hipSuccess) && ((long)occ * nCU >= GRID2);

    if (persistent_ok) {
        k_init<<<1, NTHR, 0, stream>>>(ws);
        k_main<<<GRID2, NTHR, 0, stream>>>(emb, lctx, h0, W_ih, W_hh, b_ih,
                                           b_hh, widx, enc, Wa, Wl, bl, ws, out);
    } else {
        float*  h      = ws;
        float*  ctx    = ws + 1024;
        float*  u      = ws + 2048;
        float*  energ  = ws + 3072;
        float2* part_e = (float2*)(ws + 5120);
        float2* part_l = (float2*)(ws + 6144);
        float*  logits = ws + 10240;
        k_lstm  <<<1024, 256, 0, stream>>>(emb, lctx, h0, W_ih, W_hh, b_ih, b_hh, widx, h, u, ctx);
        k_wa    <<<dim3(4, 32), 256, 0, stream>>>(Wa, h, u);
        k_energy<<<512, 256, 0, stream>>>(enc, u, energ, part_e);
        k_ctx   <<<128, 256, 0, stream>>>(enc, energ, part_e, ctx);
        k_logits<<<2000, 256, 0, stream>>>(Wl, ws /*vcat*/, bl, logits, part_l);
        k_final <<<125, 256, 0, stream>>>(logits, part_l, out);
    }
}

// Round 9
// 72.991 us; speedup vs baseline: 1.0202x; 1.0041x over previous
//
#include <hip/hip_runtime.h>
#include <hip/hip_bf16.h>
#include <math.h>

#define SEQ   2048
#define H     1024
#define VOCAB 32000
#define GRID2 2048
#define NTHR  256

__device__ inline float4 ld4(const float* p) { return *reinterpret_cast<const float4*>(p); }
__device__ inline float dot4(float4 a, float4 b) { return a.x*b.x + a.y*b.y + a.z*b.z + a.w*b.w; }
__device__ inline float sigmoidf(float x) { return 1.f / (1.f + expf(-x)); }

__device__ inline void omerge(float& m, float& s, float m2, float s2) {
    if (m2 > m) { s = s * __expf(m - m2) + s2; m = m2; }
    else if (s2 != 0.f) { s += s2 * __expf(m2 - m); }
}
__device__ inline float waveSum(float v) {
#pragma unroll
    for (int off = 32; off > 0; off >>= 1) v += __shfl_down(v, off, 64);
    return v;
}
__device__ inline void waveOmerge(float& m, float& s) {
#pragma unroll
    for (int off = 32; off > 0; off >>= 1) {
        float m2 = __shfl_down(m, off, 64), ss = __shfl_down(s, off, 64);
        omerge(m, s, m2, ss);
    }
}

// ---- sharded device-scope signal/wait (16 shards x 128 B apart) -----------
#define SHARDS 16
#define SHSTRIDE 32

__device__ inline void blockSignalSh(unsigned* f) {
    __syncthreads();
    if (threadIdx.x == 0) {
        __threadfence();
        __hip_atomic_fetch_add(&f[(blockIdx.x & (SHARDS - 1)) * SHSTRIDE], 1u,
                               __ATOMIC_RELEASE, __HIP_MEMORY_SCOPE_AGENT);
    }
}
__device__ inline unsigned shSum(unsigned* f) {
    unsigned sum = 0;
#pragma unroll
    for (int q = 0; q < SHARDS; ++q)
        sum += __hip_atomic_load(&f[q * SHSTRIDE], __ATOMIC_RELAXED,
                                 __HIP_MEMORY_SCOPE_AGENT);
    return sum;
}
__device__ inline void blockWaitSlow(unsigned* f, unsigned target) {
    if (threadIdx.x == 0) {
        int it = 0;
        while (shSum(f) < target) {
            if (it < 2)       __builtin_amdgcn_s_sleep(1);
            else if (it < 4)  __builtin_amdgcn_s_sleep(2);
            else if (it < 6)  __builtin_amdgcn_s_sleep(4);
            else if (it < 8)  __builtin_amdgcn_s_sleep(8);
            else if (it < 10) __builtin_amdgcn_s_sleep(16);
            else if (it < 12) __builtin_amdgcn_s_sleep(32);
            else              __builtin_amdgcn_s_sleep(64);
            ++it;
        }
        __threadfence();
    }
    __syncthreads();
}
__device__ inline void blockWaitFast(unsigned* f, unsigned target) {
    if (threadIdx.x == 0) {
        int it = 0;
        while (shSum(f) < target) {
            if (it < 2)      __builtin_amdgcn_s_sleep(1);
            else if (it < 4) __builtin_amdgcn_s_sleep(2);
            else if (it < 6) __builtin_amdgcn_s_sleep(4);
            else             __builtin_amdgcn_s_sleep(8);
            ++it;
        }
        __threadfence();
    }
    __syncthreads();
}

// ws layout:
//  uints [0..4096): f_hc[4] at +0,+512,+1024,+1536 (one per 256-chunk of h),
//                   f_u=+2048, f_e=+2560, f_ctx=+3072, f_l=+3584
//  floats: h=ws+4096 [1024] } vcat contiguous
//          ctx=ws+5120 [1024] }
//          u=ws+6144 [1024]
//          energ=ws+7168 [2048]
//          part_e=(float2*)(ws+9216) [256]
//          part_l=(float2*)(ws+9728) [2048]

__global__ __launch_bounds__(NTHR) void k_init(float* __restrict__ ws) {
    const int t = threadIdx.x;
    unsigned* fl = (unsigned*)ws;
    for (int k = t; k < 4096; k += NTHR) fl[k] = 0u;
    float* ctx = ws + 5120;
    float* u   = ws + 6144;
    for (int k = t; k < H; k += NTHR) { u[k] = 0.f; ctx[k] = 0.f; }
}

__global__ __launch_bounds__(NTHR, 8) void k_main(
        const float* __restrict__ emb,  const float* __restrict__ lctx,
        const float* __restrict__ h0,   const float* __restrict__ W_ih,
        const float* __restrict__ W_hh, const float* __restrict__ b_ih,
        const float* __restrict__ b_hh, const int* __restrict__ widx,
        const float* __restrict__ enc,  const float* __restrict__ Wa,
        const float* __restrict__ Wl,   const float* __restrict__ bl,
        float* __restrict__ ws, float* __restrict__ out) {
    const int bid = blockIdx.x, t = threadIdx.x;
    const int wid = t >> 6, lane = t & 63;

    unsigned* f_hc  = (unsigned*)ws;            // 4 chunk groups x 512
    unsigned* f_u   = (unsigned*)ws + 2048;
    unsigned* f_e   = (unsigned*)ws + 2560;
    unsigned* f_ctx = (unsigned*)ws + 3072;
    unsigned* f_l   = (unsigned*)ws + 3584;
    float*  vcat   = ws + 4096;                 // [2048] = h | ctx
    float*  h      = vcat;
    float*  ctx    = vcat + H;
    float*  u      = ws + 6144;
    float*  energ  = ws + 7168;
    float2* part_e = (float2*)(ws + 9216);
    float2* part_l = (float2*)(ws + 9728);

    __shared__ float  lg[12];
    __shared__ float  shh[16];
    __shared__ float  se[8];
    __shared__ float  shw[32];
    __shared__ float2 s2[4];

    // ======== P1: LSTM — blocks 0..1023, one block per output j ===========
    if (bid < 1024) {
        const int j = bid;
        const int w = widx[0];                  // int64 LE, value < 32000
        const float* xep = emb + (size_t)w * H;
        const float* wi = W_ih + (size_t)j * (2 * H);
        const float* wg = W_ih + (size_t)(j + 2 * H) * (2 * H);
        const float* wo = W_ih + (size_t)(j + 3 * H) * (2 * H);
        const float* vi = W_hh + (size_t)j * H;
        const float* vg = W_hh + (size_t)(j + 2 * H) * H;
        const float* vo = W_hh + (size_t)(j + 3 * H) * H;
        const int e = t * 4;
        float4 x0 = ld4(xep + e), x1 = ld4(lctx + e), x2 = ld4(h0 + e);
        float ai = dot4(ld4(wi + e), x0) + dot4(ld4(wi + H + e), x1) + dot4(ld4(vi + e), x2);
        float ag = dot4(ld4(wg + e), x0) + dot4(ld4(wg + H + e), x1) + dot4(ld4(vg + e), x2);
        float ao = dot4(ld4(wo + e), x0) + dot4(ld4(wo + H + e), x1) + dot4(ld4(vo + e), x2);
        ai = waveSum(ai); ag = waveSum(ag); ao = waveSum(ao);
        if (lane == 0) { lg[wid*3] = ai; lg[wid*3+1] = ag; lg[wid*3+2] = ao; }
        __syncthreads();
        if (t == 0) {
            float gi = 0.f, gg = 0.f, go = 0.f;
            for (int q = 0; q < 4; ++q) { gi += lg[q*3]; gg += lg[q*3+1]; go += lg[q*3+2]; }
            gi += b_ih[j] + b_hh[j];
            gg += b_ih[j + 2*H] + b_hh[j + 2*H];
            go += b_ih[j + 3*H] + b_hh[j + 3*H];
            float c = sigmoidf(gi) * tanhf(gg);  // c0 == 0 -> f-gate dead
            h[j] = sigmoidf(go) * tanhf(c);
        }
        blockSignalSh(f_hc + (j >> 8) * 512);    // signal my 256-chunk
    }

    if (bid >= 1024 && bid < 1280) {
        // ================= attention chain (256 blocks) ====================
        const int ab = bid - 1024;
        // --- u = Wa^T h : gated only on the chunk holding my 16 h-rows ---
        {
            const int rg = ab >> 2, kb = ab & 3;
            blockWaitFast(f_hc + (rg >> 4) * 512, 256);
            if (t < 16) shh[t] = h[rg * 16 + t];
            __syncthreads();
            const int k = kb * 256 + t;
            float acc = 0.f;
#pragma unroll
            for (int jj = 0; jj < 16; ++jj)
                acc += Wa[(size_t)(rg * 16 + jj) * H + k] * shh[jj];
            atomicAdd(&u[k], acc);
            blockSignalSh(f_u);
            blockWaitFast(f_u, 256);             // implies ALL h chunks done
        }
        // --- energies: 8 rows/block (2 per wave) + block (m,s) partial ---
        {
#pragma unroll
            for (int rr = 0; rr < 2; ++rr) {
                const int row = ab * 8 + wid * 2 + rr;
                const float* er = enc + (size_t)row * H;
                float acc = 0.f;
#pragma unroll
                for (int it = 0; it < 4; ++it) {
                    const int e = it * 256 + lane * 4;
                    acc += dot4(ld4(er + e), ld4(u + e));
                }
                acc = waveSum(acc);
                if (lane == 0) { energ[row] = acc; se[wid * 2 + rr] = acc; }
            }
            __syncthreads();
            if (t == 0) {
                float m = -INFINITY, s = 0.f;
                for (int q = 0; q < 8; ++q) omerge(m, s, se[q], 1.f);
                part_e[ab] = make_float2(m, s);
            }
            blockSignalSh(f_e);
            blockWaitFast(f_e, 256);
        }
        // --- ctx = softmax(energ) @ enc : 64 rowgroups x 32 rows ---
        {
            float2 p = part_e[t];
            float m = p.x, s = p.y;
            waveOmerge(m, s);
            if (lane == 0) s2[wid] = make_float2(m, s);
            __syncthreads();
            float M = s2[0].x, S = s2[0].y;
#pragma unroll
            for (int q = 1; q < 4; ++q) omerge(M, S, s2[q].x, s2[q].y);
            const float invS = 1.f / S;
            const int rg = ab >> 2, kb = ab & 3;
            __syncthreads();
            if (t < 32) shw[t] = __expf(energ[rg * 32 + t] - M) * invS;
            __syncthreads();
            const int k = kb * 256 + t;
            float acc = 0.f;
#pragma unroll
            for (int jj = 0; jj < 32; ++jj)
                acc += shw[jj] * enc[(size_t)(rg * 32 + jj) * H + k];
            atomicAdd(&ctx[k], acc);
            blockSignalSh(f_ctx);
            blockWaitFast(f_ctx, 256);
        }
        // --- tail rows 28672..31999 end-to-end (vcat fully available) ---
        {
            const int aw = ab * 4 + wid;          // 0..1023
            float4 xv[8];
#pragma unroll
            for (int q = 0; q < 8; ++q) xv[q] = ld4(vcat + q * 256 + lane * 4);
            float lm = -INFINITY, ls = 0.f;
#pragma unroll
            for (int rr = 0; rr < 4; ++rr) {
                if (rr < 3 || aw < 256) {
                    const int r = 28672 + aw + 1024 * rr;
                    const float* wr = Wl + (size_t)r * (2 * H);
                    float a = 0.f;
#pragma unroll
                    for (int q = 0; q < 8; ++q)
                        a += dot4(ld4(wr + q * 256 + lane * 4), xv[q]);
                    a = waveSum(a);
                    if (lane == 0) {
                        float v = a + bl[r];
                        out[r] = v;
                        omerge(lm, ls, v, 1.f);
                    }
                }
            }
            if (lane == 0) s2[wid] = make_float2(lm, ls);
            __syncthreads();
            if (t == 0) {
                float M = s2[0].x, S = s2[0].y;
#pragma unroll
                for (int q = 1; q < 4; ++q) omerge(M, S, s2[q].x, s2[q].y);
                part_l[bid] = make_float2(M, S);
            }
            blockSignalSh(f_l);
        }
    } else {
        // ==== streamers: rows 0..28671, h-half CHUNK-PIPELINED, then ctx ===
        const int sw = (bid < 1024) ? bid * 4 + wid : (bid - 256) * 4 + wid; // 0..7167
        const int r0 = sw * 4;
        const float* wr0 = Wl + (size_t)r0 * (2 * H);
        float acc4[4] = {0.f, 0.f, 0.f, 0.f};
#pragma unroll
        for (int g = 0; g < 4; ++g) {           // 4 chunks of 256 h-elements
            blockWaitFast(f_hc + g * 512, 256);
            const int e = g * 256 + lane * 4;
            float4 xh = ld4(h + e);
#pragma unroll
            for (int rr = 0; rr < 4; ++rr)
                acc4[rr] += dot4(ld4(wr0 + (size_t)rr * (2 * H) + e), xh);
        }
        blockWaitFast(f_ctx, 256);   // ---- ctx ready ----
        float4 xv[4];
#pragma unroll
        for (int q = 0; q < 4; ++q) xv[q] = ld4(ctx + q * 256 + lane * 4);
        float lm = -INFINITY, ls = 0.f;
#pragma unroll
        for (int rr = 0; rr < 4; ++rr) {
            const int r = r0 + rr;
            const float* wr = Wl + (size_t)r * (2 * H) + H;
            float a = acc4[rr];
#pragma unroll
            for (int q = 0; q < 4; ++q)
                a += dot4(ld4(wr + q * 256 + lane * 4), xv[q]);
            a = waveSum(a);
            if (lane == 0) {
                float v = a + bl[r];
                out[r] = v;
                omerge(lm, ls, v, 1.f);
            }
        }
        if (lane == 0) s2[wid] = make_float2(lm, ls);
        __syncthreads();
        if (t == 0) {
            float M = s2[0].x, S = s2[0].y;
#pragma unroll
            for (int q = 1; q < 4; ++q) omerge(M, S, s2[q].x, s2[q].y);
            part_l[bid] = make_float2(M, S);
        }
        blockSignalSh(f_l);
    }

    // ============ final: out = logits - lse (blocks 0..124) ================
    if (bid < 125) {
        blockWaitSlow(f_l, 2048);
        float m = -INFINITY, s = 0.f;
#pragma unroll
        for (int q = 0; q < 8; ++q) {
            float2 p = part_l[t + q * 256];
            omerge(m, s, p.x, p.y);
        }
        waveOmerge(m, s);
        if (lane == 0) s2[wid] = make_float2(m, s);
        __syncthreads();
        float M = s2[0].x, S = s2[0].y;
#pragma unroll
        for (int q = 1; q < 4; ++q) omerge(M, S, s2[q].x, s2[q].y);
        const float lse = M + logf(S);
        const int i = bid * 256 + t;              // 125*256 == 32000
        out[i] = out[i] - lse;
    }
}

// ======================= fallback path (round-5, proven 74.8 µs) ===========

__global__ __launch_bounds__(256) void k_lstm(
        const float* __restrict__ emb, const float* __restrict__ lctx,
        const float* __restrict__ h0,  const float* __restrict__ W_ih,
        const float* __restrict__ W_hh, const float* __restrict__ b_ih,
        const float* __restrict__ b_hh, const int* __restrict__ widx,
        float* __restrict__ h_out, float* __restrict__ u_zero,
        float* __restrict__ ctx_zero) {
    const int j = blockIdx.x, t = threadIdx.x;
    const int wid = t >> 6, lane = t & 63;
    if (j == 0) for (int k = t; k < H; k += 256) u_zero[k] = 0.f;
    if (j == 1) for (int k = t; k < H; k += 256) ctx_zero[k] = 0.f;
    const int w = widx[0];
    const float* embrow = emb + (size_t)w * H;
    const int ri = j, rg = j + 2 * H, ro = j + 3 * H;
    const float* wi_i = W_ih + (size_t)ri * (2 * H);
    const float* wi_g = W_ih + (size_t)rg * (2 * H);
    const float* wi_o = W_ih + (size_t)ro * (2 * H);
    const float* wh_i = W_hh + (size_t)ri * H;
    const float* wh_g = W_hh + (size_t)rg * H;
    const float* wh_o = W_hh + (size_t)ro * H;
    float ai = 0.f, ag = 0.f, ao = 0.f;
    { int e = t*4; float4 x = ld4(embrow+e);
      ai += dot4(ld4(wi_i+e),x); ag += dot4(ld4(wi_g+e),x); ao += dot4(ld4(wi_o+e),x); }
    { int e = t*4; float4 x = ld4(lctx+e);
      ai += dot4(ld4(wi_i+H+e),x); ag += dot4(ld4(wi_g+H+e),x); ao += dot4(ld4(wi_o+H+e),x); }
    { int e = t*4; float4 x = ld4(h0+e);
      ai += dot4(ld4(wh_i+e),x); ag += dot4(ld4(wh_g+e),x); ao += dot4(ld4(wh_o+e),x); }
    ai = waveSum(ai); ag = waveSum(ag); ao = waveSum(ao);
    __shared__ float lds[12];
    if (lane == 0) { lds[wid*3] = ai; lds[wid*3+1] = ag; lds[wid*3+2] = ao; }
    __syncthreads();
    if (t == 0) {
        float gi = 0.f, gg = 0.f, go = 0.f;
        for (int q = 0; q < 4; ++q) { gi += lds[q*3]; gg += lds[q*3+1]; go += lds[q*3+2]; }
        gi += b_ih[ri] + b_hh[ri];
        gg += b_ih[rg] + b_hh[rg];
        go += b_ih[ro] + b_hh[ro];
        float c = sigmoidf(gi) * tanhf(gg);
        h_out[j] = sigmoidf(go) * tanhf(c);
    }
}

__global__ __launch_bounds__(256) void k_wa(
        const float* __restrict__ Wa, const float* __restrict__ h,
        float* __restrict__ u) {
    const int k = blockIdx.x * 256 + threadIdx.x;
    const int j0 = blockIdx.y * 32;
    float acc = 0.f;
#pragma unroll 8
    for (int j = j0; j < j0 + 32; ++j) acc += Wa[(size_t)j * H + k] * h[j];
    atomicAdd(&u[k], acc);
}

__global__ __launch_bounds__(256) void k_energy(
        const float* __restrict__ enc, const float* __restrict__ u,
        float* __restrict__ energ, float2* __restrict__ part_e) {
    const int t = threadIdx.x, wid = t >> 6, lane = t & 63;
    const int row = blockIdx.x * 4 + wid;
    const float* er = enc + (size_t)row * H;
    float acc = 0.f;
#pragma unroll
    for (int it = 0; it < 4; ++it) { int e = it*256 + lane*4; acc += dot4(ld4(er+e), ld4(u+e)); }
    acc = waveSum(acc);
    __shared__ float se[4];
    if (lane == 0) { energ[row] = acc; se[wid] = acc; }
    __syncthreads();
    if (t == 0) {
        float m = fmaxf(fmaxf(se[0], se[1]), fmaxf(se[2], se[3]));
        float s = __expf(se[0]-m) + __expf(se[1]-m) + __expf(se[2]-m) + __expf(se[3]-m);
        part_e[blockIdx.x] = make_float2(m, s);
    }
}

__global__ __launch_bounds__(256) void k_ctx(
        const float* __restrict__ enc, const float* __restrict__ energ,
        const float2* __restrict__ part_e, float* __restrict__ ctx) {
    const int t = threadIdx.x, wid = t >> 6, lane = t & 63;
    __shared__ float2 s2[4];
    __shared__ float sh[64];
    float2 a = part_e[t], b = part_e[t + 256];
    float m = a.x, s = a.y;
    omerge(m, s, b.x, b.y);
    waveOmerge(m, s);
    if (lane == 0) s2[wid] = make_float2(m, s);
    __syncthreads();
    float M = s2[0].x, S = s2[0].y;
#pragma unroll
    for (int q = 1; q < 4; ++q) omerge(M, S, s2[q].x, s2[q].y);
    const float invS = 1.f / S;
    const int j0 = (blockIdx.x >> 2) * 64;
    __syncthreads();
    if (t < 64) sh[t] = __expf(energ[j0 + t] - M) * invS;
    __syncthreads();
    const int k = (blockIdx.x & 3) * 256 + t;
    float acc = 0.f;
#pragma unroll 8
    for (int jj = 0; jj < 64; ++jj) acc += sh[jj] * enc[(size_t)(j0 + jj) * H + k];
    atomicAdd(&ctx[k], acc);
}

__global__ __launch_bounds__(256) void k_logits(
        const float* __restrict__ Wl, const float* __restrict__ vcat,
        const float* __restrict__ bl, float* __restrict__ logits,
        float2* __restrict__ part_l) {
    const int t = threadIdx.x, wid = t >> 6, lane = t & 63;
    const int gw = blockIdx.x * 4 + wid;
    float4 xv[8];
#pragma unroll
    for (int q = 0; q < 8; ++q) xv[q] = ld4(vcat + q * 256 + lane * 4);
    float lm = -INFINITY, ls = 0.f;
#pragma unroll
    for (int rr = 0; rr < 4; ++rr) {
        const int row = gw * 4 + rr;
        const float* wr = Wl + (size_t)row * (2 * H);
        float acc = 0.f;
#pragma unroll
        for (int q = 0; q < 8; ++q)
            acc += dot4(ld4(wr + q * 256 + lane * 4), xv[q]);
        acc = waveSum(acc);
        if (lane == 0) {
            float v = acc + bl[row];
            logits[row] = v;
            omerge(lm, ls, v, 1.f);
        }
    }
    __shared__ float2 s2[4];
    if (lane == 0) s2[wid] = make_float2(lm, ls);
    __syncthreads();
    if (t == 0) {
        float M = s2[0].x, S = s2[0].y;
#pragma unroll
        for (int q = 1; q < 4; ++q) omerge(M, S, s2[q].x, s2[q].y);
        part_l[blockIdx.x] = make_float2(M, S);
    }
}

__global__ __launch_bounds__(256) void k_final(
        const float* __restrict__ logits, const float2* __restrict__ part_l,
        float* __restrict__ out) {
    const int t = threadIdx.x, wid = t >> 6, lane = t & 63;
    __shared__ float2 s2[4];
    float m = -INFINITY, s = 0.f;
    for (int i = t; i < 2000; i += 256) {
        float2 p = part_l[i];
        omerge(m, s, p.x, p.y);
    }
    waveOmerge(m, s);
    if (lane == 0) s2[wid] = make_float2(m, s);
    __syncthreads();
    float M = s2[0].x, S = s2[0].y;
#pragma unroll
    for (int q = 1; q < 4; ++q) omerge(M, S, s2[q].x, s2[q].y);
    const float lse = M + logf(S);
    const int i = blockIdx.x * 256 + t;
    out[i] = logits[i] - lse;
}

extern "C" void kernel_launch(void* const* d_in, const int* in_sizes, int n_in,
                              void* d_out, int out_size, void* d_ws, size_t ws_size,
                              hipStream_t stream) {
    const int*   widx = (const int*)d_in[0];
    const float* lctx = (const float*)d_in[1];
    const float* h0   = (const float*)d_in[2];
    const float* enc  = (const float*)d_in[3];
    const float* emb  = (const float*)d_in[4];
    const float* W_ih = (const float*)d_in[5];
    const float* W_hh = (const float*)d_in[6];
    const float* b_ih = (const float*)d_in[7];
    const float* b_hh = (const float*)d_in[8];
    const float* Wa   = (const float*)d_in[9];
    // d_in[10] (ba): dropped — constant shift under softmax
    const float* Wl   = (const float*)d_in[11];
    const float* bl   = (const float*)d_in[12];
    float* out = (float*)d_out;
    float* ws  = (float*)d_ws;

    // deadlock guard: persistent path requires all GRID2 blocks co-resident
    int occ = 0, nCU = 0, dev = 0;
    hipGetDevice(&dev);
    hipDeviceGetAttribute(&nCU, hipDeviceAttributeMultiprocessorCount, dev);
    hipError_t oe = hipOccupancyMaxActiveBlocksPerMultiprocessor(
        &occ, (const void*)k_main, NTHR, 0);
    const bool persistent_ok = (oe == hipSuccess) && ((long)occ * nCU >= GRID2);

    if (persistent_ok) {
        k_init<<<1, NTHR, 0, stream>>>(ws);
        k_main<<<GRID2, NTHR, 0, stream>>>(emb, lctx, h0, W_ih, W_hh, b_ih,
                                           b_hh, widx, enc, Wa, Wl, bl, ws, out);
    } else {
        float*  h      = ws;
        float*  ctx    = ws + 1024;
        float*  u      = ws + 2048;
        float*  energ  = ws + 3072;
        float2* part_e = (float2*)(ws + 5120);
        float2* part_l = (float2*)(ws + 6144);
        float*  logits = ws + 10240;
        k_lstm  <<<1024, 256, 0, stream>>>(emb, lctx, h0, W_ih, W_hh, b_ih, b_hh, widx, h, u, ctx);
        k_wa    <<<dim3(4, 32), 256, 0, stream>>>(Wa, h, u);
        k_energy<<<512, 256, 0, stream>>>(enc, u, energ, part_e);
        k_ctx   <<<128, 256, 0, stream>>>(enc, energ, part_e, ctx);
        k_logits<<<2000, 256, 0, stream>>>(Wl, ws /*vcat*/, bl, logits, part_l);
        k_final <<<125, 256, 0, stream>>>(logits, part_l, out);
    }
}